// Round 7
// baseline (63.788 us; speedup 1.0000x reference)
//
#include <hip/hip_runtime.h>
#include <math.h>

#define SEQ_LEN 4096
#define KSZ 128
#define OUT_LEN 3969
#define BATCH 8192
#define NB 1024          // main grid blocks
#define NB2 16           // colreduce blocks

// R5 main, unchanged (measured best). One wave = one row, 2 rows/wave,
// no barriers in the row loop, 16 float4 loads in flight, shfl_xor
// butterfly, redundant sigmoid on all lanes, edge gradients in registers.
// THIS ROUND: launched TWICE back-to-back as a timing probe — second run
// overwrites partial with identical values (deterministic), and
// main_steady = T_total - T_R5.
__global__ __launch_bounds__(256, 4) void conv1d_train_main(
    const float* __restrict__ x, const float* __restrict__ y,
    const float* __restrict__ kern, const float* __restrict__ bias,
    float* __restrict__ partial)
{
    __shared__ float P[KSZ];      // inclusive prefix sums of kernel
    __shared__ float sl[4][256];  // per-wave partials for block combine

    const int tid  = threadIdx.x;
    const int wave = tid >> 6;
    const int lane = tid & 63;

    if (tid < KSZ) P[tid] = kern[tid];
    __syncthreads();
#pragma unroll
    for (int off = 1; off < KSZ; off <<= 1) {   // Hillis-Steele scan
        float v = 0.f;
        if (tid < KSZ) {
            v = P[tid];
            if (tid >= off) v += P[tid - off];
        }
        __syncthreads();
        if (tid < KSZ) P[tid] = v;
        __syncthreads();
    }
    const float ksum = P[KSZ - 1];
    const float bs   = bias[0];

    // Per-lane edge-correction weights.
    // head lane l<32: elems j=4l..4l+3, weight P[j]-ksum  (j=127 -> 0)
    // tail lane l>=32: elem 3968+4(l-32)+q, m=elem-3969, weight -P[m]; m=-1 -> 0
    float w0, w1, w2, w3;
    if (lane < 32) {
        const int j = 4 * lane;
        w0 = P[j] - ksum; w1 = P[j + 1] - ksum;
        w2 = P[j + 2] - ksum; w3 = P[j + 3] - ksum;
    } else {
        const int m = 4 * (lane - 32) - 1;
        w0 = (m >= 0) ? -P[m] : 0.f;
        w1 = -P[m + 1]; w2 = -P[m + 2]; w3 = -P[m + 3];
    }

    float g0 = 0.f, g1 = 0.f, g2 = 0.f, g3 = 0.f;  // dconv-weighted edge accum
    float C0 = 0.f, db = 0.f;

    const int wg = blockIdx.x * 4 + wave;

    for (int b = wg; b < BATCH; b += NB * 4) {
        const float4* xr = reinterpret_cast<const float4*>(x + (size_t)b * SEQ_LEN);
        float4 r[16];
#pragma unroll
        for (int i = 0; i < 16; ++i) r[i] = xr[i * 64 + lane];
        const float yv = y[b];                       // broadcast load

        float tot = 0.f;
#pragma unroll
        for (int i = 0; i < 16; ++i) tot += (r[i].x + r[i].y) + (r[i].z + r[i].w);

        const float4 e = (lane < 32) ? r[0] : r[15];
        float corr = ((w0 * e.x + w1 * e.y) + (w2 * e.z + w3 * e.w));

        float t = tot, c = corr;
#pragma unroll
        for (int off = 1; off < 64; off <<= 1) {
            t += __shfl_xor(t, off, 64);
            c += __shfl_xor(c, off, 64);
        }
        // all lanes now hold identical t, c
        const float logits = (ksum * t + c) * (1.f / (float)OUT_LEN) + bs;
        const float sig    = 1.f / (1.f + expf(-logits));
        const float dconv  = (sig - yv) * (1.f / (float)OUT_LEN);

        g0 += dconv * e.x; g1 += dconv * e.y;
        g2 += dconv * e.z; g3 += dconv * e.w;
        C0 += dconv * t;   db += dconv;
    }

    // Per-wave writeout to LDS: [0..126]=G, [127]=C0, [128..254]=H, [255]=db
    if (lane < 32) {
        const int j = 4 * lane;
        sl[wave][j]     = g0;
        sl[wave][j + 1] = g1;
        sl[wave][j + 2] = g2;
        if (j + 3 < 127) sl[wave][j + 3] = g3;   // skip unused G[127]
    } else {
        const int s0 = 4 * lane - 1;             // slot = 128 + m
        if (lane > 32) sl[wave][s0] = g0;        // lane 32 q=0 -> m=-1, skip
        sl[wave][s0 + 1] = g1;
        sl[wave][s0 + 2] = g2;
        sl[wave][s0 + 3] = g3;                   // lane 63 -> slot 254
    }
    if (lane == 0) { sl[wave][127] = C0; sl[wave][255] = db; }
    __syncthreads();
    if (tid < 256) {
        const float s = (sl[0][tid] + sl[1][tid]) + (sl[2][tid] + sl[3][tid]);
        partial[(size_t)blockIdx.x * 256 + tid] = s;   // coalesced 1KB/block
    }
}

// Stage 2 (R5, unchanged): 16 blocks x 1024 threads stream the 1024x256
// partial matrix fully coalesced -> partial2[16][256].
__global__ __launch_bounds__(1024) void conv1d_train_colreduce(
    const float* __restrict__ partial, float* __restrict__ partial2)
{
    const int col  = threadIdx.x & 255;
    const int rsub = threadIdx.x >> 8;          // 0..3
    const int base = blockIdx.x * 64;

    float a = 0.f;
#pragma unroll
    for (int j = 0; j < 16; ++j)
        a += partial[(size_t)(base + j * 4 + rsub) * 256 + col];  // coalesced

    __shared__ float sl[4][256];
    sl[rsub][col] = a;
    __syncthreads();
    if (threadIdx.x < 256) {
        const int t = threadIdx.x;
        partial2[(size_t)blockIdx.x * 256 + t] =
            (sl[0][t] + sl[1][t]) + (sl[2][t] + sl[3][t]);
    }
}

// Stage 3 (R5, unchanged): one block. Sum 16x256 partials, 127-step scan,
// write kernel_new (128) + bias_new.
__global__ __launch_bounds__(256) void conv1d_train_finalize(
    const float* __restrict__ partial2,
    const float* __restrict__ kern, const float* __restrict__ bias,
    float* __restrict__ out)
{
    __shared__ float colsum[256];
    const int tid = threadIdx.x;

    float a = 0.f;
#pragma unroll
    for (int g = 0; g < NB2; ++g) a += partial2[(size_t)g * 256 + tid];
    colsum[tid] = a;
    __syncthreads();

    if (tid < 128) {
        const float C0 = colsum[127];
        float pre = 0.f, suf = 0.f;
        for (int j = 0; j < 127; ++j) {
            const float g = colsum[j];           // broadcast
            const float h = colsum[128 + j];
            if (j < tid)  pre += g;
            if (j >= tid) suf += h;
        }
        const float dk = (C0 - pre - suf) * (1.f / (float)BATCH);
        out[tid] = kern[tid] - dk;
    }
    if (tid == 0) {
        const float db = colsum[255] * ((float)OUT_LEN / (float)BATCH);
        out[128] = bias[0] - db;
    }
}

extern "C" void kernel_launch(void* const* d_in, const int* in_sizes, int n_in,
                              void* d_out, int out_size, void* d_ws, size_t ws_size,
                              hipStream_t stream) {
    (void)in_sizes; (void)n_in; (void)out_size; (void)ws_size;
    const float* x    = (const float*)d_in[0];
    const float* y    = (const float*)d_in[1];
    const float* kern = (const float*)d_in[2];
    const float* bias = (const float*)d_in[3];
    float* out = (float*)d_out;

    // ws layout: partial[NB*256] floats, then partial2[NB2*256] floats.
    float* partial  = (float*)d_ws;
    float* partial2 = partial + (size_t)NB * 256;

    // TIMING PROBE: main launched twice. Second run recomputes identical
    // partials (deterministic). main_steady = T_this_round - T_R5(40.2us).
    hipLaunchKernelGGL(conv1d_train_main, dim3(NB), dim3(256), 0, stream,
                       x, y, kern, bias, partial);
    hipLaunchKernelGGL(conv1d_train_main, dim3(NB), dim3(256), 0, stream,
                       x, y, kern, bias, partial);
    hipLaunchKernelGGL(conv1d_train_colreduce, dim3(NB2), dim3(1024), 0, stream,
                       partial, partial2);
    hipLaunchKernelGGL(conv1d_train_finalize, dim3(1), dim3(256), 0, stream,
                       partial2, kern, bias, out);
}

// Round 8
// 46.673 us; speedup vs baseline: 1.3667x; 1.3667x over previous
//
#include <hip/hip_runtime.h>
#include <math.h>

#define SEQ_LEN 4096
#define KSZ 128
#define OUT_LEN 3969
#define BATCH 8192
#define NB 1024          // main grid blocks
#define TAIL_NB 16       // tail kernel blocks

// R5 main, byte-identical (measured: 23.6us steady-state via R7 probe).
// One wave = one row, 2 rows/wave, no barriers in the row loop, 16 float4
// loads in flight, shfl_xor butterfly, redundant sigmoid on all lanes,
// edge gradients in registers, coalesced 1KB partial per block.
__global__ __launch_bounds__(256, 4) void conv1d_train_main(
    const float* __restrict__ x, const float* __restrict__ y,
    const float* __restrict__ kern, const float* __restrict__ bias,
    float* __restrict__ partial)
{
    __shared__ float P[KSZ];      // inclusive prefix sums of kernel
    __shared__ float sl[4][256];  // per-wave partials for block combine

    const int tid  = threadIdx.x;
    const int wave = tid >> 6;
    const int lane = tid & 63;

    if (tid < KSZ) P[tid] = kern[tid];
    __syncthreads();
#pragma unroll
    for (int off = 1; off < KSZ; off <<= 1) {   // Hillis-Steele scan
        float v = 0.f;
        if (tid < KSZ) {
            v = P[tid];
            if (tid >= off) v += P[tid - off];
        }
        __syncthreads();
        if (tid < KSZ) P[tid] = v;
        __syncthreads();
    }
    const float ksum = P[KSZ - 1];
    const float bs   = bias[0];

    // Per-lane edge-correction weights.
    // head lane l<32: elems j=4l..4l+3, weight P[j]-ksum  (j=127 -> 0)
    // tail lane l>=32: elem 3968+4(l-32)+q, m=elem-3969, weight -P[m]; m=-1 -> 0
    float w0, w1, w2, w3;
    if (lane < 32) {
        const int j = 4 * lane;
        w0 = P[j] - ksum; w1 = P[j + 1] - ksum;
        w2 = P[j + 2] - ksum; w3 = P[j + 3] - ksum;
    } else {
        const int m = 4 * (lane - 32) - 1;
        w0 = (m >= 0) ? -P[m] : 0.f;
        w1 = -P[m + 1]; w2 = -P[m + 2]; w3 = -P[m + 3];
    }

    float g0 = 0.f, g1 = 0.f, g2 = 0.f, g3 = 0.f;  // dconv-weighted edge accum
    float C0 = 0.f, db = 0.f;

    const int wg = blockIdx.x * 4 + wave;

    for (int b = wg; b < BATCH; b += NB * 4) {
        const float4* xr = reinterpret_cast<const float4*>(x + (size_t)b * SEQ_LEN);
        float4 r[16];
#pragma unroll
        for (int i = 0; i < 16; ++i) r[i] = xr[i * 64 + lane];
        const float yv = y[b];                       // broadcast load

        float tot = 0.f;
#pragma unroll
        for (int i = 0; i < 16; ++i) tot += (r[i].x + r[i].y) + (r[i].z + r[i].w);

        const float4 e = (lane < 32) ? r[0] : r[15];
        float corr = ((w0 * e.x + w1 * e.y) + (w2 * e.z + w3 * e.w));

        float t = tot, c = corr;
#pragma unroll
        for (int off = 1; off < 64; off <<= 1) {
            t += __shfl_xor(t, off, 64);
            c += __shfl_xor(c, off, 64);
        }
        // all lanes now hold identical t, c
        const float logits = (ksum * t + c) * (1.f / (float)OUT_LEN) + bs;
        const float sig    = 1.f / (1.f + expf(-logits));
        const float dconv  = (sig - yv) * (1.f / (float)OUT_LEN);

        g0 += dconv * e.x; g1 += dconv * e.y;
        g2 += dconv * e.z; g3 += dconv * e.w;
        C0 += dconv * t;   db += dconv;
    }

    // Per-wave writeout to LDS: [0..126]=G, [127]=C0, [128..254]=H, [255]=db
    if (lane < 32) {
        const int j = 4 * lane;
        sl[wave][j]     = g0;
        sl[wave][j + 1] = g1;
        sl[wave][j + 2] = g2;
        if (j + 3 < 127) sl[wave][j + 3] = g3;   // skip unused G[127]
    } else {
        const int s0 = 4 * lane - 1;             // slot = 128 + m
        if (lane > 32) sl[wave][s0] = g0;        // lane 32 q=0 -> m=-1, skip
        sl[wave][s0 + 1] = g1;
        sl[wave][s0 + 2] = g2;
        sl[wave][s0 + 3] = g3;                   // lane 63 -> slot 254
    }
    if (lane == 0) { sl[wave][127] = C0; sl[wave][255] = db; }
    __syncthreads();
    if (tid < 256) {
        const float s = (sl[0][tid] + sl[1][tid]) + (sl[2][tid] + sl[3][tid]);
        partial[(size_t)blockIdx.x * 256 + tid] = s;   // coalesced 1KB/block
    }
}

// Merged tail (single change vs R5): 16 blocks x 1024 threads stream the
// 1024x256 partial matrix fully coalesced -> partial2[16][256]; the
// last-arriving block (atomic counter; no reset needed: +16 per launch,
// exactly one old==15 mod 16 for any start value) sums the 16 rows, does
// the one-time 127-step prefix/suffix scan, writes the 129 outputs.
__global__ __launch_bounds__(1024) void conv1d_train_tail(
    const float* __restrict__ partial, float* __restrict__ partial2,
    unsigned* __restrict__ counter,
    const float* __restrict__ kern, const float* __restrict__ bias,
    float* __restrict__ out)
{
    __shared__ float sl[4][256];
    __shared__ float colsum[256];
    __shared__ unsigned lastFlag;

    const int tid  = threadIdx.x;
    const int col  = tid & 255;
    const int rsub = tid >> 8;                  // 0..3
    const int base = blockIdx.x * 64;

    float a = 0.f;
#pragma unroll
    for (int j = 0; j < 16; ++j)
        a += partial[(size_t)(base + j * 4 + rsub) * 256 + col];  // coalesced

    sl[rsub][col] = a;
    __syncthreads();
    if (tid < 256)
        partial2[(size_t)blockIdx.x * 256 + tid] =
            (sl[0][tid] + sl[1][tid]) + (sl[2][tid] + sl[3][tid]);

    __threadfence();            // release partial2
    __syncthreads();
    if (tid == 0) {
        const unsigned old = atomicAdd(counter, 1u);
        lastFlag = ((old & 15u) == 15u) ? 1u : 0u;
    }
    __syncthreads();
    if (!lastFlag) return;

    __threadfence();            // acquire
    if (tid < 256) {
        float s = 0.f;
#pragma unroll
        for (int g = 0; g < TAIL_NB; ++g) s += partial2[(size_t)g * 256 + tid];
        colsum[tid] = s;
    }
    __syncthreads();

    if (tid < 128) {
        const float C0 = colsum[127];
        float pre = 0.f, suf = 0.f;
        for (int j = 0; j < 127; ++j) {
            const float g = colsum[j];           // broadcast
            const float h = colsum[128 + j];
            if (j < tid)  pre += g;
            if (j >= tid) suf += h;
        }
        const float dk = (C0 - pre - suf) * (1.f / (float)BATCH);
        out[tid] = kern[tid] - dk;
    }
    if (tid == 0) {
        const float dbo = colsum[255] * ((float)OUT_LEN / (float)BATCH);
        out[128] = bias[0] - dbo;
    }
}

extern "C" void kernel_launch(void* const* d_in, const int* in_sizes, int n_in,
                              void* d_out, int out_size, void* d_ws, size_t ws_size,
                              hipStream_t stream) {
    (void)in_sizes; (void)n_in; (void)out_size; (void)ws_size;
    const float* x    = (const float*)d_in[0];
    const float* y    = (const float*)d_in[1];
    const float* kern = (const float*)d_in[2];
    const float* bias = (const float*)d_in[3];
    float* out = (float*)d_out;

    // ws layout: partial[NB*256], partial2[TAIL_NB*256], counter.
    float*    partial  = (float*)d_ws;
    float*    partial2 = partial + (size_t)NB * 256;
    unsigned* counter  = (unsigned*)(partial2 + (size_t)TAIL_NB * 256);

    hipLaunchKernelGGL(conv1d_train_main, dim3(NB), dim3(256), 0, stream,
                       x, y, kern, bias, partial);
    hipLaunchKernelGGL(conv1d_train_tail, dim3(TAIL_NB), dim3(1024), 0, stream,
                       partial, partial2, counter, kern, bias, out);
}

// Round 9
// 41.074 us; speedup vs baseline: 1.5530x; 1.1363x over previous
//
#include <hip/hip_runtime.h>
#include <math.h>

#define SEQ_LEN 4096
#define KSZ 128
#define OUT_LEN 3969
#define BATCH 8192
#define NB 1024          // main grid blocks
#define NREP 8           // accumulator replicas (caps per-address contention)

#define SCALE_F   1.099511627776e12f      // 2^40
#define INV_SCALE 9.094947017729282e-13   // 2^-40

// ---- DPP wave-64 sum, result broadcast wave-uniform via readlane 63 ----
// (R6-verified.) row_shr 1/2/4/8 + row_bcast:15 + row_bcast:31, lane 63
// holds the full sum; invalid-lane reads contribute 0 (bound_ctrl=1).
template <int CTRL>
__device__ __forceinline__ float dpp_add(float x) {
    const int m = __builtin_amdgcn_update_dpp(0, __float_as_int(x), CTRL, 0xf, 0xf, true);
    return x + __int_as_float(m);
}
__device__ __forceinline__ float wave_sum_uniform(float x) {
    x = dpp_add<0x111>(x);   // row_shr:1
    x = dpp_add<0x112>(x);   // row_shr:2
    x = dpp_add<0x114>(x);   // row_shr:4
    x = dpp_add<0x118>(x);   // row_shr:8
    x = dpp_add<0x142>(x);   // row_bcast:15
    x = dpp_add<0x143>(x);   // row_bcast:31
    return __int_as_float(__builtin_amdgcn_readlane(__float_as_int(x), 63));
}

// Main pass: one wave = one row, 2 rows/wave, no barriers in the row loop.
// 16 float4 loads in flight, DPP reduce (won the R6/R8 A/B by ~2us),
// redundant sigmoid on all lanes, edge gradients in registers.
// Writeout: block partial (256 floats) -> int64 scaled 2^40 -> atomicAdd
// into replica blockIdx&7. Integer adds are exact and commutative ->
// deterministic result with no fences and no second reduction kernel.
__global__ __launch_bounds__(256, 4) void conv1d_train_main(
    const float* __restrict__ x, const float* __restrict__ y,
    const float* __restrict__ kern, const float* __restrict__ bias,
    unsigned long long* __restrict__ accum)
{
    __shared__ float P[KSZ];      // inclusive prefix sums of kernel
    __shared__ float sl[4][256];  // per-wave partials for block combine

    const int tid  = threadIdx.x;
    const int wave = tid >> 6;
    const int lane = tid & 63;

    if (tid < KSZ) P[tid] = kern[tid];
    __syncthreads();
#pragma unroll
    for (int off = 1; off < KSZ; off <<= 1) {   // Hillis-Steele scan
        float v = 0.f;
        if (tid < KSZ) {
            v = P[tid];
            if (tid >= off) v += P[tid - off];
        }
        __syncthreads();
        if (tid < KSZ) P[tid] = v;
        __syncthreads();
    }
    const float ksum = P[KSZ - 1];
    const float bs   = bias[0];

    // Per-lane edge-correction weights.
    // head lane l<32: elems j=4l..4l+3, weight P[j]-ksum  (j=127 -> 0)
    // tail lane l>=32: elem 3968+4(l-32)+q, m=elem-3969, weight -P[m]; m=-1 -> 0
    float w0, w1, w2, w3;
    if (lane < 32) {
        const int j = 4 * lane;
        w0 = P[j] - ksum; w1 = P[j + 1] - ksum;
        w2 = P[j + 2] - ksum; w3 = P[j + 3] - ksum;
    } else {
        const int m = 4 * (lane - 32) - 1;
        w0 = (m >= 0) ? -P[m] : 0.f;
        w1 = -P[m + 1]; w2 = -P[m + 2]; w3 = -P[m + 3];
    }

    float g0 = 0.f, g1 = 0.f, g2 = 0.f, g3 = 0.f;  // dconv-weighted edge accum
    float C0 = 0.f, db = 0.f;

    const int wg = blockIdx.x * 4 + wave;

    for (int b = wg; b < BATCH; b += NB * 4) {
        const float4* xr = reinterpret_cast<const float4*>(x + (size_t)b * SEQ_LEN);
        float4 r[16];
#pragma unroll
        for (int i = 0; i < 16; ++i) r[i] = xr[i * 64 + lane];
        const float yv = y[b];                       // broadcast load

        float tot = 0.f;
#pragma unroll
        for (int i = 0; i < 16; ++i) tot += (r[i].x + r[i].y) + (r[i].z + r[i].w);

        const float4 e = (lane < 32) ? r[0] : r[15];
        const float corr = ((w0 * e.x + w1 * e.y) + (w2 * e.z + w3 * e.w));

        const float t = wave_sum_uniform(tot);       // wave-uniform scalars
        const float c = wave_sum_uniform(corr);

        const float logits = (ksum * t + c) * (1.f / (float)OUT_LEN) + bs;
        const float sig    = 1.f / (1.f + expf(-logits));
        const float dconv  = (sig - yv) * (1.f / (float)OUT_LEN);

        g0 += dconv * e.x; g1 += dconv * e.y;
        g2 += dconv * e.z; g3 += dconv * e.w;
        C0 += dconv * t;   db += dconv;
    }

    // Per-wave writeout to LDS: [0..126]=G, [127]=C0, [128..254]=H, [255]=db
    if (lane < 32) {
        const int j = 4 * lane;
        sl[wave][j]     = g0;
        sl[wave][j + 1] = g1;
        sl[wave][j + 2] = g2;
        if (j + 3 < 127) sl[wave][j + 3] = g3;   // skip unused G[127]
    } else {
        const int s0 = 4 * lane - 1;             // slot = 128 + m
        if (lane > 32) sl[wave][s0] = g0;        // lane 32 q=0 -> m=-1, skip
        sl[wave][s0 + 1] = g1;
        sl[wave][s0 + 2] = g2;
        sl[wave][s0 + 3] = g3;                   // lane 63 -> slot 254
    }
    if (lane == 0) {
        // C0/db accumulated from wave-uniform values: lane 0's copy is the
        // wave's value.
        sl[wave][127] = C0; sl[wave][255] = db;
    }
    __syncthreads();
    if (tid < 256) {
        const float s = (sl[0][tid] + sl[1][tid]) + (sl[2][tid] + sl[3][tid]);
        const long long q = llroundf(s * SCALE_F);   // exact, commutative
        atomicAdd(&accum[(size_t)(blockIdx.x & (NREP - 1)) * 256 + tid],
                  (unsigned long long)q);
    }
}

// Finalize: one block. Integer-sum the NREP replicas per column (exact),
// convert back to float, 127-step prefix/suffix scan, write kernel_new
// (128) + bias_new (1).
__global__ __launch_bounds__(256) void conv1d_train_finalize(
    const unsigned long long* __restrict__ accum,
    const float* __restrict__ kern, const float* __restrict__ bias,
    float* __restrict__ out)
{
    __shared__ float colsum[256];
    const int tid = threadIdx.x;

    long long s = 0;
#pragma unroll
    for (int r = 0; r < NREP; ++r)
        s += (long long)accum[(size_t)r * 256 + tid];
    colsum[tid] = (float)((double)s * INV_SCALE);
    __syncthreads();

    if (tid < 128) {
        const float C0 = colsum[127];
        float pre = 0.f, suf = 0.f;
        for (int j = 0; j < 127; ++j) {
            const float g = colsum[j];           // broadcast
            const float h = colsum[128 + j];
            if (j < tid)  pre += g;
            if (j >= tid) suf += h;
        }
        const float dk = (C0 - pre - suf) * (1.f / (float)BATCH);
        out[tid] = kern[tid] - dk;
    }
    if (tid == 0) {
        const float db = colsum[255] * ((float)OUT_LEN / (float)BATCH);
        out[128] = bias[0] - db;
    }
}

extern "C" void kernel_launch(void* const* d_in, const int* in_sizes, int n_in,
                              void* d_out, int out_size, void* d_ws, size_t ws_size,
                              hipStream_t stream) {
    (void)in_sizes; (void)n_in; (void)out_size; (void)ws_size;
    const float* x    = (const float*)d_in[0];
    const float* y    = (const float*)d_in[1];
    const float* kern = (const float*)d_in[2];
    const float* bias = (const float*)d_in[3];
    float* out = (float*)d_out;

    // ws layout: accum[NREP*256] int64 (16 KB).
    unsigned long long* accum = (unsigned long long*)d_ws;

    // Zero the accumulator every launch (memset node is graph-capturable;
    // the harness itself enqueues hipMemsetAsync).
    hipMemsetAsync(accum, 0, (size_t)NREP * 256 * sizeof(unsigned long long),
                   stream);
    hipLaunchKernelGGL(conv1d_train_main, dim3(NB), dim3(256), 0, stream,
                       x, y, kern, bias, accum);
    hipLaunchKernelGGL(conv1d_train_finalize, dim3(1), dim3(256), 0, stream,
                       accum, kern, bias, out);
}

// Round 10
// 38.913 us; speedup vs baseline: 1.6393x; 1.0555x over previous
//
#include <hip/hip_runtime.h>
#include <math.h>

#define SEQ_LEN 4096
#define KSZ 128
#define OUT_LEN 3969
#define BATCH 8192
#define NB_MAIN 256      // main grid: 1 block per CU
#define NWAVES 16        // 1024 threads per block

// ---- DPP wave-64 sum, result broadcast wave-uniform via readlane 63 ----
// (A/B verified R6 vs R8: ~2us faster than shfl_xor butterfly.)
template <int CTRL>
__device__ __forceinline__ float dpp_add(float x) {
    const int m = __builtin_amdgcn_update_dpp(0, __float_as_int(x), CTRL, 0xf, 0xf, true);
    return x + __int_as_float(m);
}
__device__ __forceinline__ float wave_sum_uniform(float x) {
    x = dpp_add<0x111>(x);   // row_shr:1
    x = dpp_add<0x112>(x);   // row_shr:2
    x = dpp_add<0x114>(x);   // row_shr:4
    x = dpp_add<0x118>(x);   // row_shr:8
    x = dpp_add<0x142>(x);   // row_bcast:15
    x = dpp_add<0x143>(x);   // row_bcast:31
    return __int_as_float(__builtin_amdgcn_readlane(__float_as_int(x), 63));
}

// Main pass: 256 blocks x 1024 threads (16 waves = 16 waves/CU, same wave
// count as the R7-measured 23.6us config). One wave = one row, 2 rows/wave
// (256*16*2 = 8192 exactly), no barriers in the row loop, 16 float4 loads
// in flight, DPP reduce, edge gradients in registers.
// amdgpu_waves_per_eu(4,4) pins occupancy at exactly 4 waves/EU so the
// compiler keeps the full 128-VGPR budget (R4 lesson: launch_bounds alone
// lets the compiler squeeze VGPRs for more occupancy, serializing r[16]).
// Block partial = 256 floats -> partial matrix is 256x256 (256KB), 4x
// smaller than R5's, making a single-block tail cheap.
__global__ __launch_bounds__(1024)
__attribute__((amdgpu_waves_per_eu(4, 4)))
void conv1d_train_main(
    const float* __restrict__ x, const float* __restrict__ y,
    const float* __restrict__ kern, const float* __restrict__ bias,
    float* __restrict__ partial)
{
    __shared__ float P[KSZ];          // inclusive prefix sums of kernel
    __shared__ float sl[NWAVES][256]; // per-wave partials for block combine

    const int tid  = threadIdx.x;
    const int wave = tid >> 6;
    const int lane = tid & 63;

    if (tid < KSZ) P[tid] = kern[tid];
    __syncthreads();
#pragma unroll
    for (int off = 1; off < KSZ; off <<= 1) {   // Hillis-Steele scan
        float v = 0.f;
        if (tid < KSZ) {
            v = P[tid];
            if (tid >= off) v += P[tid - off];
        }
        __syncthreads();
        if (tid < KSZ) P[tid] = v;
        __syncthreads();
    }
    const float ksum = P[KSZ - 1];
    const float bs   = bias[0];

    // Per-lane edge-correction weights (verified R2).
    // head lane l<32: elems j=4l..4l+3, weight P[j]-ksum  (j=127 -> 0)
    // tail lane l>=32: elem 3968+4(l-32)+q, m=elem-3969, weight -P[m]; m=-1 -> 0
    float w0, w1, w2, w3;
    if (lane < 32) {
        const int j = 4 * lane;
        w0 = P[j] - ksum; w1 = P[j + 1] - ksum;
        w2 = P[j + 2] - ksum; w3 = P[j + 3] - ksum;
    } else {
        const int m = 4 * (lane - 32) - 1;
        w0 = (m >= 0) ? -P[m] : 0.f;
        w1 = -P[m + 1]; w2 = -P[m + 2]; w3 = -P[m + 3];
    }

    float g0 = 0.f, g1 = 0.f, g2 = 0.f, g3 = 0.f;  // dconv-weighted edge accum
    float C0 = 0.f, db = 0.f;

    const int wg = blockIdx.x * NWAVES + wave;       // 0..4095

    for (int b = wg; b < BATCH; b += NB_MAIN * NWAVES) {   // 2 iterations
        const float4* xr = reinterpret_cast<const float4*>(x + (size_t)b * SEQ_LEN);
        float4 r[16];
#pragma unroll
        for (int i = 0; i < 16; ++i) r[i] = xr[i * 64 + lane];
        const float yv = y[b];                       // broadcast load

        float tot = 0.f;
#pragma unroll
        for (int i = 0; i < 16; ++i) tot += (r[i].x + r[i].y) + (r[i].z + r[i].w);

        const float4 e = (lane < 32) ? r[0] : r[15];
        const float corr = ((w0 * e.x + w1 * e.y) + (w2 * e.z + w3 * e.w));

        const float t = wave_sum_uniform(tot);       // wave-uniform scalars
        const float c = wave_sum_uniform(corr);

        const float logits = (ksum * t + c) * (1.f / (float)OUT_LEN) + bs;
        const float sig    = 1.f / (1.f + expf(-logits));
        const float dconv  = (sig - yv) * (1.f / (float)OUT_LEN);

        g0 += dconv * e.x; g1 += dconv * e.y;
        g2 += dconv * e.z; g3 += dconv * e.w;
        C0 += dconv * t;   db += dconv;
    }

    // Per-wave writeout to LDS: [0..126]=G, [127]=C0, [128..254]=H, [255]=db
    if (lane < 32) {
        const int j = 4 * lane;
        sl[wave][j]     = g0;
        sl[wave][j + 1] = g1;
        sl[wave][j + 2] = g2;
        if (j + 3 < 127) sl[wave][j + 3] = g3;   // skip unused G[127]
    } else {
        const int s0 = 4 * lane - 1;             // slot = 128 + m
        if (lane > 32) sl[wave][s0] = g0;        // lane 32 q=0 -> m=-1, skip
        sl[wave][s0 + 1] = g1;
        sl[wave][s0 + 2] = g2;
        sl[wave][s0 + 3] = g3;                   // lane 63 -> slot 254
    }
    if (lane == 0) { sl[wave][127] = C0; sl[wave][255] = db; }
    __syncthreads();
    if (tid < 256) {
        float s = 0.f;
#pragma unroll
        for (int w = 0; w < NWAVES; ++w) s += sl[w][tid];
        partial[(size_t)blockIdx.x * 256 + tid] = s;   // coalesced 1KB/block
    }
}

// Tail: ONE block, 1024 threads. Reads the 256x256 partial matrix (256KB,
// coalesced; dispatch boundary guarantees visibility — no fences), column
// sums via 4 slices x 64 rows, then the one-time 127-step prefix/suffix
// scan, write kernel_new (128) + bias_new (1).
__global__ __launch_bounds__(1024) void conv1d_train_tail(
    const float* __restrict__ partial,
    const float* __restrict__ kern, const float* __restrict__ bias,
    float* __restrict__ out)
{
    __shared__ float slr[4][256];
    __shared__ float colsum[256];

    const int tid   = threadIdx.x;
    const int col   = tid & 255;
    const int slice = tid >> 8;                 // 0..3, 64 rows each
    const int base  = slice * 64;

    float a0 = 0.f, a1 = 0.f, a2 = 0.f, a3 = 0.f;
#pragma unroll
    for (int j = 0; j < 64; j += 4) {           // independent load chains
        a0 += partial[(size_t)(base + j + 0) * 256 + col];
        a1 += partial[(size_t)(base + j + 1) * 256 + col];
        a2 += partial[(size_t)(base + j + 2) * 256 + col];
        a3 += partial[(size_t)(base + j + 3) * 256 + col];
    }
    slr[slice][col] = (a0 + a1) + (a2 + a3);
    __syncthreads();

    if (tid < 256)
        colsum[tid] = (slr[0][tid] + slr[1][tid]) + (slr[2][tid] + slr[3][tid]);
    __syncthreads();

    if (tid < 128) {
        const float C0 = colsum[127];
        float pre = 0.f, suf = 0.f;
        for (int j = 0; j < 127; ++j) {
            const float g = colsum[j];           // broadcast
            const float h = colsum[128 + j];
            if (j < tid)  pre += g;
            if (j >= tid) suf += h;
        }
        const float dk = (C0 - pre - suf) * (1.f / (float)BATCH);
        out[tid] = kern[tid] - dk;
    }
    if (tid == 0) {
        const float db = colsum[255] * ((float)OUT_LEN / (float)BATCH);
        out[128] = bias[0] - db;
    }
}

extern "C" void kernel_launch(void* const* d_in, const int* in_sizes, int n_in,
                              void* d_out, int out_size, void* d_ws, size_t ws_size,
                              hipStream_t stream) {
    (void)in_sizes; (void)n_in; (void)out_size; (void)ws_size;
    const float* x    = (const float*)d_in[0];
    const float* y    = (const float*)d_in[1];
    const float* kern = (const float*)d_in[2];
    const float* bias = (const float*)d_in[3];
    float* out = (float*)d_out;

    // ws layout: partial[NB_MAIN*256] floats (256KB), fully overwritten
    // every call — no initialization needed.
    float* partial = (float*)d_ws;

    hipLaunchKernelGGL(conv1d_train_main, dim3(NB_MAIN), dim3(1024), 0, stream,
                       x, y, kern, bias, partial);
    hipLaunchKernelGGL(conv1d_train_tail, dim3(1), dim3(1024), 0, stream,
                       partial, kern, bias, out);
}

// Round 11
// 38.896 us; speedup vs baseline: 1.6400x; 1.0004x over previous
//
#include <hip/hip_runtime.h>
#include <math.h>

#define SEQ_LEN 4096
#define KSZ 128
#define OUT_LEN 3969
#define BATCH 8192
#define NB_MAIN 256      // main grid: 1 block per CU
#define NWAVES 16        // 1024 threads per block

// ---- DPP wave-64 sum, result broadcast wave-uniform via readlane 63 ----
// (A/B verified R6 vs R8: ~2us faster than shfl_xor butterfly.)
template <int CTRL>
__device__ __forceinline__ float dpp_add(float x) {
    const int m = __builtin_amdgcn_update_dpp(0, __float_as_int(x), CTRL, 0xf, 0xf, true);
    return x + __int_as_float(m);
}
__device__ __forceinline__ float wave_sum_uniform(float x) {
    x = dpp_add<0x111>(x);   // row_shr:1
    x = dpp_add<0x112>(x);   // row_shr:2
    x = dpp_add<0x114>(x);   // row_shr:4
    x = dpp_add<0x118>(x);   // row_shr:8
    x = dpp_add<0x142>(x);   // row_bcast:15
    x = dpp_add<0x143>(x);   // row_bcast:31
    return __int_as_float(__builtin_amdgcn_readlane(__float_as_int(x), 63));
}

// Main pass (R10, byte-identical): 256 blocks x 1024 threads, 16 waves/CU.
// One wave = one row, 2 rows/wave, no barriers in the row loop, 16 float4
// loads in flight, DPP reduce, edge gradients in registers.
// amdgpu_waves_per_eu(4,4) pins the full 128-VGPR budget (R4 lesson).
__global__ __launch_bounds__(1024)
__attribute__((amdgpu_waves_per_eu(4, 4)))
void conv1d_train_main(
    const float* __restrict__ x, const float* __restrict__ y,
    const float* __restrict__ kern, const float* __restrict__ bias,
    float* __restrict__ partial)
{
    __shared__ float P[KSZ];          // inclusive prefix sums of kernel
    __shared__ float sl[NWAVES][256]; // per-wave partials for block combine

    const int tid  = threadIdx.x;
    const int wave = tid >> 6;
    const int lane = tid & 63;

    if (tid < KSZ) P[tid] = kern[tid];
    __syncthreads();
#pragma unroll
    for (int off = 1; off < KSZ; off <<= 1) {   // Hillis-Steele scan
        float v = 0.f;
        if (tid < KSZ) {
            v = P[tid];
            if (tid >= off) v += P[tid - off];
        }
        __syncthreads();
        if (tid < KSZ) P[tid] = v;
        __syncthreads();
    }
    const float ksum = P[KSZ - 1];
    const float bs   = bias[0];

    // Per-lane edge-correction weights (verified R2).
    // head lane l<32: elems j=4l..4l+3, weight P[j]-ksum  (j=127 -> 0)
    // tail lane l>=32: elem 3968+4(l-32)+q, m=elem-3969, weight -P[m]; m=-1 -> 0
    float w0, w1, w2, w3;
    if (lane < 32) {
        const int j = 4 * lane;
        w0 = P[j] - ksum; w1 = P[j + 1] - ksum;
        w2 = P[j + 2] - ksum; w3 = P[j + 3] - ksum;
    } else {
        const int m = 4 * (lane - 32) - 1;
        w0 = (m >= 0) ? -P[m] : 0.f;
        w1 = -P[m + 1]; w2 = -P[m + 2]; w3 = -P[m + 3];
    }

    float g0 = 0.f, g1 = 0.f, g2 = 0.f, g3 = 0.f;  // dconv-weighted edge accum
    float C0 = 0.f, db = 0.f;

    const int wg = blockIdx.x * NWAVES + wave;       // 0..4095

    for (int b = wg; b < BATCH; b += NB_MAIN * NWAVES) {   // 2 iterations
        const float4* xr = reinterpret_cast<const float4*>(x + (size_t)b * SEQ_LEN);
        float4 r[16];
#pragma unroll
        for (int i = 0; i < 16; ++i) r[i] = xr[i * 64 + lane];
        const float yv = y[b];                       // broadcast load

        float tot = 0.f;
#pragma unroll
        for (int i = 0; i < 16; ++i) tot += (r[i].x + r[i].y) + (r[i].z + r[i].w);

        const float4 e = (lane < 32) ? r[0] : r[15];
        const float corr = ((w0 * e.x + w1 * e.y) + (w2 * e.z + w3 * e.w));

        const float t = wave_sum_uniform(tot);       // wave-uniform scalars
        const float c = wave_sum_uniform(corr);

        const float logits = (ksum * t + c) * (1.f / (float)OUT_LEN) + bs;
        const float sig    = 1.f / (1.f + expf(-logits));
        const float dconv  = (sig - yv) * (1.f / (float)OUT_LEN);

        g0 += dconv * e.x; g1 += dconv * e.y;
        g2 += dconv * e.z; g3 += dconv * e.w;
        C0 += dconv * t;   db += dconv;
    }

    // Per-wave writeout to LDS: [0..126]=G, [127]=C0, [128..254]=H, [255]=db
    if (lane < 32) {
        const int j = 4 * lane;
        sl[wave][j]     = g0;
        sl[wave][j + 1] = g1;
        sl[wave][j + 2] = g2;
        if (j + 3 < 127) sl[wave][j + 3] = g3;   // skip unused G[127]
    } else {
        const int s0 = 4 * lane - 1;             // slot = 128 + m
        if (lane > 32) sl[wave][s0] = g0;        // lane 32 q=0 -> m=-1, skip
        sl[wave][s0 + 1] = g1;
        sl[wave][s0 + 2] = g2;
        sl[wave][s0 + 3] = g3;                   // lane 63 -> slot 254
    }
    if (lane == 0) { sl[wave][127] = C0; sl[wave][255] = db; }
    __syncthreads();
    if (tid < 256) {
        float s = 0.f;
#pragma unroll
        for (int w = 0; w < NWAVES; ++w) s += sl[w][tid];
        partial[(size_t)blockIdx.x * 256 + tid] = s;   // coalesced 1KB/block
    }
}

// Tail (single change vs R10): float4 loads. One block, 1024 threads.
// Thread t owns column group 4k..4k+3 (k = t&63) and row slice (t>>6):
// 16 float4 loads, 4 independent accumulator chains -> 4x fewer load
// instructions and 4x in-flight bytes vs R10's scalar loads. Then LDS
// combine across the 16 slices, 127-step prefix/suffix scan, write out.
__global__ __launch_bounds__(1024) void conv1d_train_tail(
    const float* __restrict__ partial,
    const float* __restrict__ kern, const float* __restrict__ bias,
    float* __restrict__ out)
{
    __shared__ float slr[NWAVES][256];
    __shared__ float colsum[256];

    const int tid   = threadIdx.x;
    const int k     = tid & 63;                 // column group -> cols 4k..4k+3
    const int slice = tid >> 6;                 // 0..15, 16 rows each
    const int rbase = slice * 16;

    float4 a0 = {0.f, 0.f, 0.f, 0.f}, a1 = {0.f, 0.f, 0.f, 0.f};
    float4 a2 = {0.f, 0.f, 0.f, 0.f}, a3 = {0.f, 0.f, 0.f, 0.f};
    const float4* p4 = reinterpret_cast<const float4*>(partial);
#pragma unroll
    for (int j = 0; j < 16; j += 4) {           // 4 independent chains
        const float4 v0 = p4[(size_t)(rbase + j + 0) * 64 + k];
        const float4 v1 = p4[(size_t)(rbase + j + 1) * 64 + k];
        const float4 v2 = p4[(size_t)(rbase + j + 2) * 64 + k];
        const float4 v3 = p4[(size_t)(rbase + j + 3) * 64 + k];
        a0.x += v0.x; a0.y += v0.y; a0.z += v0.z; a0.w += v0.w;
        a1.x += v1.x; a1.y += v1.y; a1.z += v1.z; a1.w += v1.w;
        a2.x += v2.x; a2.y += v2.y; a2.z += v2.z; a2.w += v2.w;
        a3.x += v3.x; a3.y += v3.y; a3.z += v3.z; a3.w += v3.w;
    }
    float4 a;
    a.x = (a0.x + a1.x) + (a2.x + a3.x);
    a.y = (a0.y + a1.y) + (a2.y + a3.y);
    a.z = (a0.z + a1.z) + (a2.z + a3.z);
    a.w = (a0.w + a1.w) + (a2.w + a3.w);
    slr[slice][4 * k + 0] = a.x;
    slr[slice][4 * k + 1] = a.y;
    slr[slice][4 * k + 2] = a.z;
    slr[slice][4 * k + 3] = a.w;
    __syncthreads();

    if (tid < 256) {
        float s = 0.f;
#pragma unroll
        for (int w = 0; w < NWAVES; ++w) s += slr[w][tid];
        colsum[tid] = s;
    }
    __syncthreads();

    if (tid < 128) {
        const float C0 = colsum[127];
        float pre = 0.f, suf = 0.f;
        for (int j = 0; j < 127; ++j) {
            const float g = colsum[j];           // broadcast
            const float h = colsum[128 + j];
            if (j < tid)  pre += g;
            if (j >= tid) suf += h;
        }
        const float dk = (C0 - pre - suf) * (1.f / (float)BATCH);
        out[tid] = kern[tid] - dk;
    }
    if (tid == 0) {
        const float db = colsum[255] * ((float)OUT_LEN / (float)BATCH);
        out[128] = bias[0] - db;
    }
}

extern "C" void kernel_launch(void* const* d_in, const int* in_sizes, int n_in,
                              void* d_out, int out_size, void* d_ws, size_t ws_size,
                              hipStream_t stream) {
    (void)in_sizes; (void)n_in; (void)out_size; (void)ws_size;
    const float* x    = (const float*)d_in[0];
    const float* y    = (const float*)d_in[1];
    const float* kern = (const float*)d_in[2];
    const float* bias = (const float*)d_in[3];
    float* out = (float*)d_out;

    // ws layout: partial[NB_MAIN*256] floats (256KB), fully overwritten
    // every call — no initialization needed.
    float* partial = (float*)d_ws;

    hipLaunchKernelGGL(conv1d_train_main, dim3(NB_MAIN), dim3(1024), 0, stream,
                       x, y, kern, bias, partial);
    hipLaunchKernelGGL(conv1d_train_tail, dim3(1), dim3(1024), 0, stream,
                       partial, kern, bias, out);
}